// Round 2
// baseline (1206.141 us; speedup 1.0000x reference)
//
#include <hip/hip_runtime.h>
#include <math.h>

#define N_ROWS 2048
#define DIM    512
#define VOCAB  32000
#define S_LEN  400
#define BATCH  32

// ---------------- kernel 1: p_copy = sigmoid(hidden @ Wc^T + bc) ----------------
__global__ void pcopy_kernel(const float* __restrict__ hidden,
                             const float* __restrict__ Wc,
                             const float* __restrict__ bc,
                             float* __restrict__ pc) {
    int n = blockIdx.x;
    int lane = threadIdx.x;                     // 64 threads = 1 wave
    const float4* h4 = reinterpret_cast<const float4*>(hidden + (size_t)n * DIM);
    const float4* w4 = reinterpret_cast<const float4*>(Wc);
    float acc = 0.f;
    #pragma unroll
    for (int i = lane; i < DIM / 4; i += 64) {
        float4 a = h4[i], b = w4[i];
        acc += a.x * b.x + a.y * b.y + a.z * b.z + a.w * b.w;
    }
    for (int off = 32; off > 0; off >>= 1)
        acc += __shfl_down(acc, off);
    if (lane == 0) {
        float z = acc + bc[0];
        pc[n] = 1.f / (1.f + expf(-z));
    }
}

// ---------------- kernel 2: logits = hidden @ W^T + b  -> d_out ----------------
// A: [M, K] row-major (hidden), B: [V, K] row-major (W)  => C[m,v] = sum_k A[m,k]*B[v,k]
#define BM 64
#define BN 64
#define BK 16

__global__ __launch_bounds__(256) void gemm_kernel(const float* __restrict__ A,
                                                   const float* __restrict__ B,
                                                   const float* __restrict__ bias,
                                                   float* __restrict__ C) {
    __shared__ float As[BK][BM + 4];   // +4 pad: rows stay 16B-aligned (68*4=272=16*17)
    __shared__ float Bs[BK][BN + 4];

    const int bm = blockIdx.y * BM;
    const int bn = blockIdx.x * BN;
    const int tid = threadIdx.x;

    // loader: 256 threads, each loads one float4 along K of a 64x16 tile
    const int lr = tid >> 2;          // 0..63 : row within tile
    const int lk = (tid & 3) * 4;     // 0,4,8,12 : k within tile
    // compute: 16x16 thread grid, each owns 4x4 outputs
    const int tm = (tid >> 4) * 4;
    const int tn = (tid & 15) * 4;

    float acc[4][4] = {};

    for (int k0 = 0; k0 < DIM; k0 += BK) {
        float4 a  = *reinterpret_cast<const float4*>(A + (size_t)(bm + lr) * DIM + k0 + lk);
        float4 bv = *reinterpret_cast<const float4*>(B + (size_t)(bn + lr) * DIM + k0 + lk);
        As[lk + 0][lr] = a.x;  As[lk + 1][lr] = a.y;  As[lk + 2][lr] = a.z;  As[lk + 3][lr] = a.w;
        Bs[lk + 0][lr] = bv.x; Bs[lk + 1][lr] = bv.y; Bs[lk + 2][lr] = bv.z; Bs[lk + 3][lr] = bv.w;
        __syncthreads();
        #pragma unroll
        for (int kk = 0; kk < BK; ++kk) {
            float4 av = *reinterpret_cast<const float4*>(&As[kk][tm]);
            float4 bw = *reinterpret_cast<const float4*>(&Bs[kk][tn]);
            float am[4] = {av.x, av.y, av.z, av.w};
            float bb[4] = {bw.x, bw.y, bw.z, bw.w};
            #pragma unroll
            for (int i = 0; i < 4; ++i)
                #pragma unroll
                for (int j = 0; j < 4; ++j)
                    acc[i][j] = fmaf(am[i], bb[j], acc[i][j]);
        }
        __syncthreads();
    }

    #pragma unroll
    for (int i = 0; i < 4; ++i) {
        float4 v;
        v.x = acc[i][0] + bias[bn + tn + 0];
        v.y = acc[i][1] + bias[bn + tn + 1];
        v.z = acc[i][2] + bias[bn + tn + 2];
        v.w = acc[i][3] + bias[bn + tn + 3];
        *reinterpret_cast<float4*>(C + (size_t)(bm + tm + i) * VOCAB + bn + tn) = v;
    }
}

// ---------------- kernel 3: per-row max and sum(exp(l - max)) ----------------
__global__ __launch_bounds__(256) void rowstat_kernel(const float* __restrict__ logits,
                                                      float* __restrict__ rowmax,
                                                      float* __restrict__ rowsum) {
    const int n = blockIdx.x;
    const int tid = threadIdx.x;
    const float* row = logits + (size_t)n * VOCAB;
    __shared__ float red[256];

    float m = -INFINITY;
    for (int i = tid; i < VOCAB; i += 256) m = fmaxf(m, row[i]);
    red[tid] = m; __syncthreads();
    for (int s = 128; s > 0; s >>= 1) {
        if (tid < s) red[tid] = fmaxf(red[tid], red[tid + s]);
        __syncthreads();
    }
    m = red[0];
    __syncthreads();

    float sum = 0.f;
    for (int i = tid; i < VOCAB; i += 256) sum += expf(row[i] - m);
    red[tid] = sum; __syncthreads();
    for (int s = 128; s > 0; s >>= 1) {
        if (tid < s) red[tid] += red[tid + s];
        __syncthreads();
    }
    if (tid == 0) { rowmax[n] = m; rowsum[n] = red[0]; }
}

// ---------------- kernel 4: out = exp(l - m)/sum * (1 - pc)  (in place) ----------------
__global__ void scale_kernel(float* __restrict__ out,
                             const float* __restrict__ pc,
                             const float* __restrict__ rowmax,
                             const float* __restrict__ rowsum) {
    const size_t total4 = (size_t)N_ROWS * VOCAB / 4;
    for (size_t idx = (size_t)blockIdx.x * blockDim.x + threadIdx.x;
         idx < total4;
         idx += (size_t)gridDim.x * blockDim.x) {
        const int n = (int)((idx * 4) / VOCAB);
        const float m = rowmax[n];
        const float f = (1.f - pc[n]) / rowsum[n];
        float4 v = reinterpret_cast<float4*>(out)[idx];
        v.x = expf(v.x - m) * f;
        v.y = expf(v.y - m) * f;
        v.z = expf(v.z - m) * f;
        v.w = expf(v.w - m) * f;
        reinterpret_cast<float4*>(out)[idx] = v;
    }
}

// ---------------- kernel 5: scatter out[n, src[s, n%B]] += attn[n,s] * pc[n] ----------------
// src is int64 in the reference but the harness passes integers as int32.
__global__ void scatter_kernel(float* __restrict__ out,
                               const float* __restrict__ attn,
                               const int* __restrict__ src,
                               const float* __restrict__ pc) {
    const int tid = blockIdx.x * blockDim.x + threadIdx.x;
    if (tid >= N_ROWS * S_LEN) return;
    const int n = tid / S_LEN;
    const int s = tid % S_LEN;
    const int b = n % BATCH;
    const int v = src[s * BATCH + b];
    atomicAdd(out + (size_t)n * VOCAB + v, attn[(size_t)n * S_LEN + s] * pc[n]);
}

// ---------------- kernel 6: out = log(max(out, 1e-20)) ----------------
__global__ void log_kernel(float* __restrict__ out) {
    const size_t total4 = (size_t)N_ROWS * VOCAB / 4;
    for (size_t idx = (size_t)blockIdx.x * blockDim.x + threadIdx.x;
         idx < total4;
         idx += (size_t)gridDim.x * blockDim.x) {
        float4 v = reinterpret_cast<float4*>(out)[idx];
        v.x = logf(fmaxf(v.x, 1e-20f));
        v.y = logf(fmaxf(v.y, 1e-20f));
        v.z = logf(fmaxf(v.z, 1e-20f));
        v.w = logf(fmaxf(v.w, 1e-20f));
        reinterpret_cast<float4*>(out)[idx] = v;
    }
}

extern "C" void kernel_launch(void* const* d_in, const int* in_sizes, int n_in,
                              void* d_out, int out_size, void* d_ws, size_t ws_size,
                              hipStream_t stream) {
    const float* hidden = (const float*)d_in[0];   // [N, D]
    const float* attn   = (const float*)d_in[1];   // [N, S]
    const int*   src    = (const int*)d_in[2];     // [S, B, 1] (int32 on device)
    const float* W      = (const float*)d_in[3];   // [V, D]
    const float* bias   = (const float*)d_in[4];   // [V]
    const float* Wc     = (const float*)d_in[5];   // [1, D]
    const float* bc     = (const float*)d_in[6];   // [1]
    float* out = (float*)d_out;                    // [N, V]

    float* pc     = (float*)d_ws;                  // [N]
    float* rowmax = pc + N_ROWS;                   // [N]
    float* rowsum = rowmax + N_ROWS;               // [N]

    // 1) p_copy
    pcopy_kernel<<<N_ROWS, 64, 0, stream>>>(hidden, Wc, bc, pc);

    // 2) logits -> d_out
    dim3 ggrid(VOCAB / BN, N_ROWS / BM);
    gemm_kernel<<<ggrid, 256, 0, stream>>>(hidden, W, bias, out);

    // 3) row stats
    rowstat_kernel<<<N_ROWS, 256, 0, stream>>>(out, rowmax, rowsum);

    // 4) softmax scale (in place)
    scale_kernel<<<4096, 256, 0, stream>>>(out, pc, rowmax, rowsum);

    // 5) copy-attention scatter
    scatter_kernel<<<(N_ROWS * S_LEN + 255) / 256, 256, 0, stream>>>(out, attn, src, pc);

    // 6) log clip (in place)
    log_kernel<<<4096, 256, 0, stream>>>(out);
}

// Round 3
// 474.662 us; speedup vs baseline: 2.5411x; 2.5411x over previous
//
#include <hip/hip_runtime.h>
#include <math.h>
#include <stdint.h>

#define N_ROWS 2048
#define DIM    512
#define VOCAB  32000
#define S_LEN  400
#define BATCH  32

typedef __attribute__((ext_vector_type(8))) short short8;
typedef __attribute__((ext_vector_type(4))) float floatx4;

__device__ inline unsigned short f32_to_bf16(float f) {
    union { float f; unsigned u; } v; v.f = f;
    unsigned u = v.u;
    return (unsigned short)((u + 0x7FFFu + ((u >> 16) & 1u)) >> 16);   // RNE
}

// ---------------- kernel 0: f32 -> bf16 cast (vectorized) ----------------
__global__ void cast_bf16_kernel(const float* __restrict__ src,
                                 unsigned short* __restrict__ dst, unsigned n4) {
    for (unsigned i = blockIdx.x * blockDim.x + threadIdx.x; i < n4;
         i += gridDim.x * blockDim.x) {
        float4 v = reinterpret_cast<const float4*>(src)[i];
        ushort4 o;
        o.x = f32_to_bf16(v.x); o.y = f32_to_bf16(v.y);
        o.z = f32_to_bf16(v.z); o.w = f32_to_bf16(v.w);
        reinterpret_cast<ushort4*>(dst)[i] = o;
    }
}

// ---------------- kernel 1: p_copy = sigmoid(hidden @ Wc^T + bc) ----------------
__global__ void pcopy_kernel(const float* __restrict__ hidden,
                             const float* __restrict__ Wc,
                             const float* __restrict__ bc,
                             float* __restrict__ pc) {
    int n = blockIdx.x;
    int lane = threadIdx.x;                     // 64 threads = 1 wave
    const float4* h4 = reinterpret_cast<const float4*>(hidden + (size_t)n * DIM);
    const float4* w4 = reinterpret_cast<const float4*>(Wc);
    float acc = 0.f;
    #pragma unroll
    for (int i = lane; i < DIM / 4; i += 64) {
        float4 a = h4[i], b = w4[i];
        acc += a.x * b.x + a.y * b.y + a.z * b.z + a.w * b.w;
    }
    for (int off = 32; off > 0; off >>= 1)
        acc += __shfl_down(acc, off);
    if (lane == 0) {
        float z = acc + bc[0];
        pc[n] = 1.f / (1.f + expf(-z));
    }
}

// ---------------- kernel 2a: bf16 MFMA GEMM (m97 structure) ----------------
// A: [2048][512] bf16, B: [32000][512] bf16 (both K-major), C[m,v] = sum_k A[m,k]*B[v,k]
#define TBM 128
#define TBN 128
#define TBK 32

__global__ __launch_bounds__(256) void gemm_mfma_kernel(
        const unsigned short* __restrict__ A,
        const unsigned short* __restrict__ B,
        const float* __restrict__ bias,
        float* __restrict__ C) {
    __shared__ unsigned short As[TBM * TBK];   // 8 KB, linear [row][k], row stride 32
    __shared__ unsigned short Bs[TBN * TBK];   // 8 KB

    const int tid  = threadIdx.x;
    const int lane = tid & 63;
    const int w    = tid >> 6;          // wave 0..3
    const int wr   = w >> 1, wc = w & 1;

    const int bm = blockIdx.y * TBM;
    const int bn = blockIdx.x * TBN;

    const int l15 = lane & 15;
    const int kg  = lane >> 4;          // 0..3

    floatx4 acc[4][4] = {};

    for (int k0 = 0; k0 < DIM; k0 += TBK) {
        // stage A,B tiles: each 8 KB = 512 x 16B chunks; chunk = r*256 + w*64 + lane
        // LDS dest = wave-uniform base + lane*16 (HW); global src per-lane.
        #pragma unroll
        for (int r = 0; r < 2; ++r) {
            const int chunk = r * 256 + w * 64 + lane;
            const int row = chunk >> 2, cg = chunk & 3;      // 4 chunks (64B) per row
            const unsigned short* ga = A + (size_t)(bm + row) * DIM + k0 + cg * 8;
            __builtin_amdgcn_global_load_lds(
                (const __attribute__((address_space(1))) void*)ga,
                (__attribute__((address_space(3))) void*)(As + (size_t)(r * 256 + w * 64) * 8),
                16, 0, 0);
        }
        #pragma unroll
        for (int r = 0; r < 2; ++r) {
            const int chunk = r * 256 + w * 64 + lane;
            const int row = chunk >> 2, cg = chunk & 3;
            const unsigned short* gb = B + (size_t)(bn + row) * DIM + k0 + cg * 8;
            __builtin_amdgcn_global_load_lds(
                (const __attribute__((address_space(1))) void*)gb,
                (__attribute__((address_space(3))) void*)(Bs + (size_t)(r * 256 + w * 64) * 8),
                16, 0, 0);
        }
        __syncthreads();   // drains vmcnt before use

        // fragment loads: A[l&15 + m*16][kg*8 .. +8], B likewise (both K-major)
        short8 af[4], bf[4];
        #pragma unroll
        for (int m = 0; m < 4; ++m) {
            const int row = wr * 64 + m * 16 + l15;
            af[m] = *(const short8*)(As + row * TBK + kg * 8);
        }
        #pragma unroll
        for (int n = 0; n < 4; ++n) {
            const int row = wc * 64 + n * 16 + l15;
            bf[n] = *(const short8*)(Bs + row * TBK + kg * 8);
        }
        #pragma unroll
        for (int m = 0; m < 4; ++m)
            #pragma unroll
            for (int n = 0; n < 4; ++n)
                acc[m][n] = __builtin_amdgcn_mfma_f32_16x16x32_bf16(af[m], bf[n], acc[m][n], 0, 0, 0);

        __syncthreads();   // protect LDS before next-iter staging
    }

    // C/D layout: col = lane&15, row = (lane>>4)*4 + reg   [m89]
    #pragma unroll
    for (int m = 0; m < 4; ++m) {
        const int gm = bm + wr * 64 + m * 16 + kg * 4;
        #pragma unroll
        for (int n = 0; n < 4; ++n) {
            const int gn = bn + wc * 64 + n * 16 + l15;
            const float bv = bias[gn];
            #pragma unroll
            for (int r = 0; r < 4; ++r)
                C[(size_t)(gm + r) * VOCAB + gn] = acc[m][n][r] + bv;
        }
    }
}

// ---------------- kernel 2b: f32 GEMM fallback (if ws too small) ----------------
#define BM 64
#define BN 64
#define BK 16

__global__ __launch_bounds__(256) void gemm_kernel(const float* __restrict__ A,
                                                   const float* __restrict__ B,
                                                   const float* __restrict__ bias,
                                                   float* __restrict__ C) {
    __shared__ float As[BK][BM + 4];
    __shared__ float Bs[BK][BN + 4];

    const int bm = blockIdx.y * BM;
    const int bn = blockIdx.x * BN;
    const int tid = threadIdx.x;
    const int lr = tid >> 2;
    const int lk = (tid & 3) * 4;
    const int tm = (tid >> 4) * 4;
    const int tn = (tid & 15) * 4;

    float acc[4][4] = {};

    for (int k0 = 0; k0 < DIM; k0 += BK) {
        float4 a  = *reinterpret_cast<const float4*>(A + (size_t)(bm + lr) * DIM + k0 + lk);
        float4 bv = *reinterpret_cast<const float4*>(B + (size_t)(bn + lr) * DIM + k0 + lk);
        As[lk + 0][lr] = a.x;  As[lk + 1][lr] = a.y;  As[lk + 2][lr] = a.z;  As[lk + 3][lr] = a.w;
        Bs[lk + 0][lr] = bv.x; Bs[lk + 1][lr] = bv.y; Bs[lk + 2][lr] = bv.z; Bs[lk + 3][lr] = bv.w;
        __syncthreads();
        #pragma unroll
        for (int kk = 0; kk < BK; ++kk) {
            float4 av = *reinterpret_cast<const float4*>(&As[kk][tm]);
            float4 bw = *reinterpret_cast<const float4*>(&Bs[kk][tn]);
            float am[4] = {av.x, av.y, av.z, av.w};
            float bb[4] = {bw.x, bw.y, bw.z, bw.w};
            #pragma unroll
            for (int i = 0; i < 4; ++i)
                #pragma unroll
                for (int j = 0; j < 4; ++j)
                    acc[i][j] = fmaf(am[i], bb[j], acc[i][j]);
        }
        __syncthreads();
    }

    #pragma unroll
    for (int i = 0; i < 4; ++i) {
        float4 v;
        v.x = acc[i][0] + bias[bn + tn + 0];
        v.y = acc[i][1] + bias[bn + tn + 1];
        v.z = acc[i][2] + bias[bn + tn + 2];
        v.w = acc[i][3] + bias[bn + tn + 3];
        *reinterpret_cast<float4*>(C + (size_t)(bm + tm + i) * VOCAB + bn + tn) = v;
    }
}

// ---------------- kernel 3: per-row max and sum(exp(l - max)) ----------------
__global__ __launch_bounds__(256) void rowstat_kernel(const float* __restrict__ logits,
                                                      float* __restrict__ rowmax,
                                                      float* __restrict__ rowsum) {
    const int n = blockIdx.x;
    const int tid = threadIdx.x;
    const float* row = logits + (size_t)n * VOCAB;
    __shared__ float red[256];

    float m = -INFINITY;
    for (int i = tid; i < VOCAB; i += 256) m = fmaxf(m, row[i]);
    red[tid] = m; __syncthreads();
    for (int s = 128; s > 0; s >>= 1) {
        if (tid < s) red[tid] = fmaxf(red[tid], red[tid + s]);
        __syncthreads();
    }
    m = red[0];
    __syncthreads();

    float sum = 0.f;
    for (int i = tid; i < VOCAB; i += 256) sum += expf(row[i] - m);
    red[tid] = sum; __syncthreads();
    for (int s = 128; s > 0; s >>= 1) {
        if (tid < s) red[tid] += red[tid + s];
        __syncthreads();
    }
    if (tid == 0) { rowmax[n] = m; rowsum[n] = red[0]; }
}

// ---------------- kernel 4: out = exp(l - m)/sum * (1 - pc)  (in place) ----------------
__global__ void scale_kernel(float* __restrict__ out,
                             const float* __restrict__ pc,
                             const float* __restrict__ rowmax,
                             const float* __restrict__ rowsum) {
    const unsigned total4 = (unsigned)N_ROWS * (VOCAB / 4);
    for (unsigned idx = blockIdx.x * blockDim.x + threadIdx.x; idx < total4;
         idx += gridDim.x * blockDim.x) {
        const unsigned n = idx / (VOCAB / 4);         // magic-mul div
        const float m = rowmax[n];
        const float f = (1.f - pc[n]) / rowsum[n];
        float4 v = reinterpret_cast<float4*>(out)[idx];
        v.x = expf(v.x - m) * f;
        v.y = expf(v.y - m) * f;
        v.z = expf(v.z - m) * f;
        v.w = expf(v.w - m) * f;
        reinterpret_cast<float4*>(out)[idx] = v;
    }
}

// ---------------- kernel 5: scatter out[n, src[s, n%B]] += attn[n,s] * pc[n] ----------------
__global__ void scatter_kernel(float* __restrict__ out,
                               const float* __restrict__ attn,
                               const int* __restrict__ src,
                               const float* __restrict__ pc) {
    const int tid = blockIdx.x * blockDim.x + threadIdx.x;
    if (tid >= N_ROWS * S_LEN) return;
    const int n = tid / S_LEN;
    const int s = tid % S_LEN;
    const int b = n % BATCH;
    const int v = src[s * BATCH + b];
    atomicAdd(out + (size_t)n * VOCAB + v, attn[(size_t)n * S_LEN + s] * pc[n]);
}

// ---------------- kernel 6: out = log(max(out, 1e-20)) ----------------
__global__ void log_kernel(float* __restrict__ out) {
    const unsigned total4 = (unsigned)N_ROWS * (VOCAB / 4);
    for (unsigned idx = blockIdx.x * blockDim.x + threadIdx.x; idx < total4;
         idx += gridDim.x * blockDim.x) {
        float4 v = reinterpret_cast<float4*>(out)[idx];
        v.x = logf(fmaxf(v.x, 1e-20f));
        v.y = logf(fmaxf(v.y, 1e-20f));
        v.z = logf(fmaxf(v.z, 1e-20f));
        v.w = logf(fmaxf(v.w, 1e-20f));
        reinterpret_cast<float4*>(out)[idx] = v;
    }
}

extern "C" void kernel_launch(void* const* d_in, const int* in_sizes, int n_in,
                              void* d_out, int out_size, void* d_ws, size_t ws_size,
                              hipStream_t stream) {
    const float* hidden = (const float*)d_in[0];   // [N, D]
    const float* attn   = (const float*)d_in[1];   // [N, S]
    const int*   src    = (const int*)d_in[2];     // [S, B, 1] (int32 on device)
    const float* W      = (const float*)d_in[3];   // [V, D]
    const float* bias   = (const float*)d_in[4];   // [V]
    const float* Wc     = (const float*)d_in[5];   // [1, D]
    const float* bc     = (const float*)d_in[6];   // [1]
    float* out = (float*)d_out;                    // [N, V]

    const size_t wb_elems = (size_t)VOCAB * DIM;
    const size_t hb_elems = (size_t)N_ROWS * DIM;
    const size_t need = (wb_elems + hb_elems) * 2 + 3 * N_ROWS * 4 + 256;

    if (ws_size >= need) {
        unsigned short* Wb = (unsigned short*)d_ws;
        unsigned short* Hb = Wb + wb_elems;
        float* pc     = (float*)(Hb + hb_elems);
        float* rowmax = pc + N_ROWS;
        float* rowsum = rowmax + N_ROWS;

        cast_bf16_kernel<<<2048, 256, 0, stream>>>(W, Wb, (unsigned)(wb_elems / 4));
        cast_bf16_kernel<<<256, 256, 0, stream>>>(hidden, Hb, (unsigned)(hb_elems / 4));
        pcopy_kernel<<<N_ROWS, 64, 0, stream>>>(hidden, Wc, bc, pc);

        dim3 ggrid(VOCAB / TBN, N_ROWS / TBM);     // 250 x 16
        gemm_mfma_kernel<<<ggrid, 256, 0, stream>>>(Wb + wb_elems - wb_elems + 0 == 0 ? Hb : Hb, Wb, bias, out);
        // (A = hidden bf16, B = W bf16)

        rowstat_kernel<<<N_ROWS, 256, 0, stream>>>(out, rowmax, rowsum);
        scale_kernel<<<4096, 256, 0, stream>>>(out, pc, rowmax, rowsum);
        scatter_kernel<<<(N_ROWS * S_LEN + 255) / 256, 256, 0, stream>>>(out, attn, src, pc);
        log_kernel<<<4096, 256, 0, stream>>>(out);
    } else {
        float* pc     = (float*)d_ws;
        float* rowmax = pc + N_ROWS;
        float* rowsum = rowmax + N_ROWS;

        pcopy_kernel<<<N_ROWS, 64, 0, stream>>>(hidden, Wc, bc, pc);
        dim3 ggrid(VOCAB / BN, N_ROWS / BM);
        gemm_kernel<<<ggrid, 256, 0, stream>>>(hidden, W, bias, out);
        rowstat_kernel<<<N_ROWS, 256, 0, stream>>>(out, rowmax, rowsum);
        scale_kernel<<<4096, 256, 0, stream>>>(out, pc, rowmax, rowsum);
        scatter_kernel<<<(N_ROWS * S_LEN + 255) / 256, 256, 0, stream>>>(out, attn, src, pc);
        log_kernel<<<4096, 256, 0, stream>>>(out);
    }
}

// Round 4
// 460.328 us; speedup vs baseline: 2.6202x; 1.0311x over previous
//
#include <hip/hip_runtime.h>
#include <math.h>
#include <stdint.h>

#define N_ROWS 2048
#define DIM    512
#define VOCAB  32000
#define S_LEN  400
#define BATCH  32
#define NT     (VOCAB / 128)      // 250 N-tiles
#define LOG_CLIP -46.0517018598809136f   // log(1e-20)

typedef __attribute__((ext_vector_type(8))) short short8;
typedef __attribute__((ext_vector_type(4))) float floatx4;

__device__ inline unsigned short f32_to_bf16(float f) {
    union { float f; unsigned u; } v; v.f = f;
    unsigned u = v.u;
    return (unsigned short)((u + 0x7FFFu + ((u >> 16) & 1u)) >> 16);   // RNE
}

// ---------------- kernel 0: f32 -> bf16 cast (vectorized) ----------------
__global__ void cast_bf16_kernel(const float* __restrict__ src,
                                 unsigned short* __restrict__ dst, unsigned n4) {
    for (unsigned i = blockIdx.x * blockDim.x + threadIdx.x; i < n4;
         i += gridDim.x * blockDim.x) {
        float4 v = reinterpret_cast<const float4*>(src)[i];
        ushort4 o;
        o.x = f32_to_bf16(v.x); o.y = f32_to_bf16(v.y);
        o.z = f32_to_bf16(v.z); o.w = f32_to_bf16(v.w);
        reinterpret_cast<ushort4*>(dst)[i] = o;
    }
}

// ---------------- kernel 1: p_copy = sigmoid(hidden @ Wc^T + bc) ----------------
__global__ void pcopy_kernel(const float* __restrict__ hidden,
                             const float* __restrict__ Wc,
                             const float* __restrict__ bc,
                             float* __restrict__ pc) {
    int n = blockIdx.x;
    int lane = threadIdx.x;                     // 64 threads = 1 wave
    const float4* h4 = reinterpret_cast<const float4*>(hidden + (size_t)n * DIM);
    const float4* w4 = reinterpret_cast<const float4*>(Wc);
    float acc = 0.f;
    #pragma unroll
    for (int i = lane; i < DIM / 4; i += 64) {
        float4 a = h4[i], b = w4[i];
        acc += a.x * b.x + a.y * b.y + a.z * b.z + a.w * b.w;
    }
    for (int off = 32; off > 0; off >>= 1)
        acc += __shfl_down(acc, off);
    if (lane == 0) {
        float z = acc + bc[0];
        pc[n] = 1.f / (1.f + expf(-z));
    }
}

// ---------------- kernel 2a: bf16 MFMA GEMM + fused per-tile softmax partials ----
// A: [2048][512] bf16, B: [32000][512] bf16 (both K-major), C[m,v] = sum_k A[m,k]*B[v,k]
// partials[(row)*NT + bx] = {tile_row_max, tile_row_sumexp}
#define TBM 128
#define TBN 128
#define TBK 32

__global__ __launch_bounds__(256) void gemm_mfma_kernel(
        const unsigned short* __restrict__ A,
        const unsigned short* __restrict__ B,
        const float* __restrict__ bias,
        float* __restrict__ C,
        float2* __restrict__ partials) {
    __shared__ unsigned short As[TBM * TBK];   // 8 KB, linear [row][k], row stride 32
    __shared__ unsigned short Bs[TBN * TBK];   // 8 KB
    __shared__ float pmax[TBM];
    __shared__ float psum[TBM];

    const int tid  = threadIdx.x;
    const int lane = tid & 63;
    const int w    = tid >> 6;          // wave 0..3
    const int wr   = w >> 1, wc = w & 1;

    const int bm = blockIdx.y * TBM;
    const int bn = blockIdx.x * TBN;

    const int l15 = lane & 15;
    const int kg  = lane >> 4;          // 0..3

    floatx4 acc[4][4] = {};

    for (int k0 = 0; k0 < DIM; k0 += TBK) {
        // stage A,B tiles: 8 KB each = 512 x 16B chunks; chunk = r*256 + w*64 + lane
        #pragma unroll
        for (int r = 0; r < 2; ++r) {
            const int chunk = r * 256 + w * 64 + lane;
            const int row = chunk >> 2, cg = chunk & 3;      // 4 chunks (64B) per row
            const unsigned short* ga = A + (size_t)(bm + row) * DIM + k0 + cg * 8;
            __builtin_amdgcn_global_load_lds(
                (const __attribute__((address_space(1))) void*)ga,
                (__attribute__((address_space(3))) void*)(As + (size_t)(r * 256 + w * 64) * 8),
                16, 0, 0);
        }
        #pragma unroll
        for (int r = 0; r < 2; ++r) {
            const int chunk = r * 256 + w * 64 + lane;
            const int row = chunk >> 2, cg = chunk & 3;
            const unsigned short* gb = B + (size_t)(bn + row) * DIM + k0 + cg * 8;
            __builtin_amdgcn_global_load_lds(
                (const __attribute__((address_space(1))) void*)gb,
                (__attribute__((address_space(3))) void*)(Bs + (size_t)(r * 256 + w * 64) * 8),
                16, 0, 0);
        }
        __syncthreads();   // drains vmcnt before use

        short8 af[4], bf[4];
        #pragma unroll
        for (int m = 0; m < 4; ++m) {
            const int row = wr * 64 + m * 16 + l15;
            af[m] = *(const short8*)(As + row * TBK + kg * 8);
        }
        #pragma unroll
        for (int n = 0; n < 4; ++n) {
            const int row = wc * 64 + n * 16 + l15;
            bf[n] = *(const short8*)(Bs + row * TBK + kg * 8);
        }
        #pragma unroll
        for (int m = 0; m < 4; ++m)
            #pragma unroll
            for (int n = 0; n < 4; ++n)
                acc[m][n] = __builtin_amdgcn_mfma_f32_16x16x32_bf16(af[m], bf[n], acc[m][n], 0, 0, 0);

        __syncthreads();
    }

    // bias add + C write. C/D layout: col = lane&15, row = (lane>>4)*4 + reg [m89]
    #pragma unroll
    for (int m = 0; m < 4; ++m) {
        const int gm = bm + wr * 64 + m * 16 + kg * 4;
        #pragma unroll
        for (int n = 0; n < 4; ++n) {
            const int gn = bn + wc * 64 + n * 16 + l15;
            const float bv = bias[gn];
            #pragma unroll
            for (int r = 0; r < 4; ++r) {
                acc[m][n][r] += bv;
                C[(size_t)(gm + r) * VOCAB + gn] = acc[m][n][r];
            }
        }
    }

    // ---- fused per-tile softmax partials over this block's 128 columns ----
    // per (m,r): all 16 lanes of a kg-group hold the SAME row, 16 different cols;
    // max/sum over n (4 col-subtiles) then shfl over the 16-lane group.
    float vmax[4][4];
    #pragma unroll
    for (int m = 0; m < 4; ++m)
        #pragma unroll
        for (int r = 0; r < 4; ++r) {
            float v = fmaxf(fmaxf(acc[m][0][r], acc[m][1][r]),
                            fmaxf(acc[m][2][r], acc[m][3][r]));
            #pragma unroll
            for (int off = 1; off < 16; off <<= 1)
                v = fmaxf(v, __shfl_xor(v, off));
            vmax[m][r] = v;
        }
    if (wc == 0) {
        if (l15 == 0)
            #pragma unroll
            for (int m = 0; m < 4; ++m)
                #pragma unroll
                for (int r = 0; r < 4; ++r)
                    pmax[wr * 64 + m * 16 + kg * 4 + r] = vmax[m][r];
    }
    __syncthreads();
    if (wc == 1) {
        if (l15 == 0)
            #pragma unroll
            for (int m = 0; m < 4; ++m)
                #pragma unroll
                for (int r = 0; r < 4; ++r) {
                    const int rl = wr * 64 + m * 16 + kg * 4 + r;
                    pmax[rl] = fmaxf(pmax[rl], vmax[m][r]);
                }
    }
    __syncthreads();

    float vsum[4][4];
    #pragma unroll
    for (int m = 0; m < 4; ++m)
        #pragma unroll
        for (int r = 0; r < 4; ++r) {
            const float M = pmax[wr * 64 + m * 16 + kg * 4 + r];
            float s = expf(acc[m][0][r] - M) + expf(acc[m][1][r] - M)
                    + expf(acc[m][2][r] - M) + expf(acc[m][3][r] - M);
            #pragma unroll
            for (int off = 1; off < 16; off <<= 1)
                s += __shfl_xor(s, off);
            vsum[m][r] = s;
        }
    if (wc == 0) {
        if (l15 == 0)
            #pragma unroll
            for (int m = 0; m < 4; ++m)
                #pragma unroll
                for (int r = 0; r < 4; ++r)
                    psum[wr * 64 + m * 16 + kg * 4 + r] = vsum[m][r];
    }
    __syncthreads();
    if (wc == 1) {
        if (l15 == 0)
            #pragma unroll
            for (int m = 0; m < 4; ++m)
                #pragma unroll
                for (int r = 0; r < 4; ++r)
                    psum[wr * 64 + m * 16 + kg * 4 + r] += vsum[m][r];
    }
    __syncthreads();

    if (tid < TBM) {
        float2 p; p.x = pmax[tid]; p.y = psum[tid];
        partials[(size_t)(bm + tid) * NT + blockIdx.x] = p;
    }
}

// ---------------- kernel 3: merge per-tile partials -> rowmax / rowsum ----------------
__global__ __launch_bounds__(256) void merge_kernel(const float2* __restrict__ partials,
                                                    float* __restrict__ rowmax,
                                                    float* __restrict__ rowsum) {
    const int n = blockIdx.x;
    const int tid = threadIdx.x;
    __shared__ float red[256];

    float2 p = {0.f, 0.f};
    float m = -INFINITY;
    if (tid < NT) { p = partials[(size_t)n * NT + tid]; m = p.x; }
    red[tid] = m; __syncthreads();
    for (int s = 128; s > 0; s >>= 1) {
        if (tid < s) red[tid] = fmaxf(red[tid], red[tid + s]);
        __syncthreads();
    }
    const float M = red[0];
    __syncthreads();

    float s = (tid < NT) ? p.y * expf(p.x - M) : 0.f;
    red[tid] = s; __syncthreads();
    for (int st = 128; st > 0; st >>= 1) {
        if (tid < st) red[tid] += red[tid + st];
        __syncthreads();
    }
    if (tid == 0) { rowmax[n] = M; rowsum[n] = red[0]; }
}

// ---------------- kernel 4: fixup — exact values for scatter-touched elements ----
// For each row n: dedup the 400 vocab ids (owner = first occurrence), sum duplicate
// contributions, gather raw logit from C, emit (flat index, final log value).
__global__ __launch_bounds__(256) void fixup_kernel(const float* __restrict__ C,
                                                    const float* __restrict__ attn,
                                                    const int* __restrict__ src,
                                                    const float* __restrict__ pc,
                                                    const float* __restrict__ rowmax,
                                                    const float* __restrict__ rowsum,
                                                    int* __restrict__ sidx,
                                                    float* __restrict__ sval) {
    const int n = blockIdx.x;
    const int tid = threadIdx.x;
    const int b = n & (BATCH - 1);
    __shared__ int   ids[S_LEN];
    __shared__ float at[S_LEN];

    for (int s = tid; s < S_LEN; s += 256) {
        ids[s] = src[s * BATCH + b];
        at[s]  = attn[(size_t)n * S_LEN + s];
    }
    __syncthreads();

    const float m   = rowmax[n];
    const float pcn = pc[n];
    const float f   = (1.f - pcn) / rowsum[n];

    for (int s = tid; s < S_LEN; s += 256) {
        const int v = ids[s];
        bool owner = true;
        for (int t = 0; t < s; ++t)
            if (ids[t] == v) { owner = false; break; }
        int outi = -1; float val = 0.f;
        if (owner) {
            float c = 0.f;
            for (int t = s; t < S_LEN; ++t)
                if (ids[t] == v) c += at[t];
            const float l = C[(size_t)n * VOCAB + v];
            const float p = expf(l - m) * f + pcn * c;
            val = logf(fmaxf(p, 1e-20f));
            outi = n * VOCAB + v;          // < 2^26, fits int
        }
        sidx[n * S_LEN + s] = outi;
        sval[n * S_LEN + s] = val;
    }
}

// ---------------- kernel 5: fused scale+log (in place, NO transcendentals) --------
// log(max(exp(l-m)*f, 1e-20)) = max((l-m) + log f, log 1e-20)
__global__ void scalelog_kernel(float* __restrict__ out,
                                const float* __restrict__ pc,
                                const float* __restrict__ rowmax,
                                const float* __restrict__ rowsum) {
    const unsigned total4 = (unsigned)N_ROWS * (VOCAB / 4);
    for (unsigned idx = blockIdx.x * blockDim.x + threadIdx.x; idx < total4;
         idx += gridDim.x * blockDim.x) {
        const unsigned n = idx / (VOCAB / 4);
        const float m = rowmax[n];
        const float lf = logf((1.f - pc[n]) / rowsum[n]) - m;
        float4 v = reinterpret_cast<float4*>(out)[idx];
        v.x = fmaxf(v.x + lf, LOG_CLIP);
        v.y = fmaxf(v.y + lf, LOG_CLIP);
        v.z = fmaxf(v.z + lf, LOG_CLIP);
        v.w = fmaxf(v.w + lf, LOG_CLIP);
        reinterpret_cast<float4*>(out)[idx] = v;
    }
}

// ---------------- kernel 6: apply side-list (owners have unique indices) ----------
__global__ void apply_kernel(const int* __restrict__ sidx,
                             const float* __restrict__ sval,
                             float* __restrict__ out) {
    const int i = blockIdx.x * blockDim.x + threadIdx.x;
    if (i >= N_ROWS * S_LEN) return;
    const int o = sidx[i];
    if (o >= 0) out[o] = sval[i];
}

// ================= f32 fallback path (ws too small) =================
#define BM 64
#define BN 64
#define BK 16

__global__ __launch_bounds__(256) void gemm_kernel(const float* __restrict__ A,
                                                   const float* __restrict__ B,
                                                   const float* __restrict__ bias,
                                                   float* __restrict__ C) {
    __shared__ float As[BK][BM + 4];
    __shared__ float Bs[BK][BN + 4];

    const int bm = blockIdx.y * BM;
    const int bn = blockIdx.x * BN;
    const int tid = threadIdx.x;
    const int lr = tid >> 2;
    const int lk = (tid & 3) * 4;
    const int tm = (tid >> 4) * 4;
    const int tn = (tid & 15) * 4;

    float acc[4][4] = {};

    for (int k0 = 0; k0 < DIM; k0 += BK) {
        float4 a  = *reinterpret_cast<const float4*>(A + (size_t)(bm + lr) * DIM + k0 + lk);
        float4 bv = *reinterpret_cast<const float4*>(B + (size_t)(bn + lr) * DIM + k0 + lk);
        As[lk + 0][lr] = a.x;  As[lk + 1][lr] = a.y;  As[lk + 2][lr] = a.z;  As[lk + 3][lr] = a.w;
        Bs[lk + 0][lr] = bv.x; Bs[lk + 1][lr] = bv.y; Bs[lk + 2][lr] = bv.z; Bs[lk + 3][lr] = bv.w;
        __syncthreads();
        #pragma unroll
        for (int kk = 0; kk < BK; ++kk) {
            float4 av = *reinterpret_cast<const float4*>(&As[kk][tm]);
            float4 bw = *reinterpret_cast<const float4*>(&Bs[kk][tn]);
            float am[4] = {av.x, av.y, av.z, av.w};
            float bb[4] = {bw.x, bw.y, bw.z, bw.w};
            #pragma unroll
            for (int i = 0; i < 4; ++i)
                #pragma unroll
                for (int j = 0; j < 4; ++j)
                    acc[i][j] = fmaf(am[i], bb[j], acc[i][j]);
        }
        __syncthreads();
    }

    #pragma unroll
    for (int i = 0; i < 4; ++i) {
        float4 v;
        v.x = acc[i][0] + bias[bn + tn + 0];
        v.y = acc[i][1] + bias[bn + tn + 1];
        v.z = acc[i][2] + bias[bn + tn + 2];
        v.w = acc[i][3] + bias[bn + tn + 3];
        *reinterpret_cast<float4*>(C + (size_t)(bm + tm + i) * VOCAB + bn + tn) = v;
    }
}

__global__ __launch_bounds__(256) void rowstat_kernel(const float* __restrict__ logits,
                                                      float* __restrict__ rowmax,
                                                      float* __restrict__ rowsum) {
    const int n = blockIdx.x;
    const int tid = threadIdx.x;
    const float* row = logits + (size_t)n * VOCAB;
    __shared__ float red[256];

    float m = -INFINITY;
    for (int i = tid; i < VOCAB; i += 256) m = fmaxf(m, row[i]);
    red[tid] = m; __syncthreads();
    for (int s = 128; s > 0; s >>= 1) {
        if (tid < s) red[tid] = fmaxf(red[tid], red[tid + s]);
        __syncthreads();
    }
    m = red[0];
    __syncthreads();

    float sum = 0.f;
    for (int i = tid; i < VOCAB; i += 256) sum += expf(row[i] - m);
    red[tid] = sum; __syncthreads();
    for (int s = 128; s > 0; s >>= 1) {
        if (tid < s) red[tid] += red[tid + s];
        __syncthreads();
    }
    if (tid == 0) { rowmax[n] = m; rowsum[n] = red[0]; }
}

__global__ void scale_kernel(float* __restrict__ out,
                             const float* __restrict__ pc,
                             const float* __restrict__ rowmax,
                             const float* __restrict__ rowsum) {
    const unsigned total4 = (unsigned)N_ROWS * (VOCAB / 4);
    for (unsigned idx = blockIdx.x * blockDim.x + threadIdx.x; idx < total4;
         idx += gridDim.x * blockDim.x) {
        const unsigned n = idx / (VOCAB / 4);
        const float m = rowmax[n];
        const float f = (1.f - pc[n]) / rowsum[n];
        float4 v = reinterpret_cast<float4*>(out)[idx];
        v.x = expf(v.x - m) * f;
        v.y = expf(v.y - m) * f;
        v.z = expf(v.z - m) * f;
        v.w = expf(v.w - m) * f;
        reinterpret_cast<float4*>(out)[idx] = v;
    }
}

__global__ void scatter_kernel(float* __restrict__ out,
                               const float* __restrict__ attn,
                               const int* __restrict__ src,
                               const float* __restrict__ pc) {
    const int tid = blockIdx.x * blockDim.x + threadIdx.x;
    if (tid >= N_ROWS * S_LEN) return;
    const int n = tid / S_LEN;
    const int s = tid % S_LEN;
    const int b = n % BATCH;
    const int v = src[s * BATCH + b];
    atomicAdd(out + (size_t)n * VOCAB + v, attn[(size_t)n * S_LEN + s] * pc[n]);
}

__global__ void log_kernel(float* __restrict__ out) {
    const unsigned total4 = (unsigned)N_ROWS * (VOCAB / 4);
    for (unsigned idx = blockIdx.x * blockDim.x + threadIdx.x; idx < total4;
         idx += gridDim.x * blockDim.x) {
        float4 v = reinterpret_cast<float4*>(out)[idx];
        v.x = logf(fmaxf(v.x, 1e-20f));
        v.y = logf(fmaxf(v.y, 1e-20f));
        v.z = logf(fmaxf(v.z, 1e-20f));
        v.w = logf(fmaxf(v.w, 1e-20f));
        reinterpret_cast<float4*>(out)[idx] = v;
    }
}

extern "C" void kernel_launch(void* const* d_in, const int* in_sizes, int n_in,
                              void* d_out, int out_size, void* d_ws, size_t ws_size,
                              hipStream_t stream) {
    const float* hidden = (const float*)d_in[0];   // [N, D]
    const float* attn   = (const float*)d_in[1];   // [N, S]
    const int*   src    = (const int*)d_in[2];     // [S, B, 1] (int32 on device)
    const float* W      = (const float*)d_in[3];   // [V, D]
    const float* bias   = (const float*)d_in[4];   // [V]
    const float* Wc     = (const float*)d_in[5];   // [1, D]
    const float* bc     = (const float*)d_in[6];   // [1]
    float* out = (float*)d_out;                    // [N, V]

    // workspace layout (256B-aligned slots)
    const size_t wb_bytes   = (size_t)VOCAB * DIM * 2;          // 32.77 MB
    const size_t hb_bytes   = (size_t)N_ROWS * DIM * 2;         //  2.10 MB
    const size_t vec_bytes  = (size_t)N_ROWS * 4;               //  8 KB each
    const size_t part_bytes = (size_t)N_ROWS * NT * 8;          //  4.10 MB
    const size_t side_bytes = (size_t)N_ROWS * S_LEN * 4;       //  3.28 MB each

    size_t off = 0;
    auto alloc = [&](size_t bytes) { size_t o = off; off = (off + bytes + 255) & ~(size_t)255; return o; };
    char* ws = (char*)d_ws;
    const size_t o_wb   = alloc(wb_bytes);
    const size_t o_hb   = alloc(hb_bytes);
    const size_t o_pc   = alloc(vec_bytes);
    const size_t o_max  = alloc(vec_bytes);
    const size_t o_sum  = alloc(vec_bytes);
    const size_t o_part = alloc(part_bytes);
    const size_t o_sidx = alloc(side_bytes);
    const size_t o_sval = alloc(side_bytes);
    const size_t need = off;

    if (ws_size >= need) {
        unsigned short* Wb = (unsigned short*)(ws + o_wb);
        unsigned short* Hb = (unsigned short*)(ws + o_hb);
        float*  pc       = (float*)(ws + o_pc);
        float*  rowmax   = (float*)(ws + o_max);
        float*  rowsum   = (float*)(ws + o_sum);
        float2* partials = (float2*)(ws + o_part);
        int*    sidx     = (int*)(ws + o_sidx);
        float*  sval     = (float*)(ws + o_sval);

        cast_bf16_kernel<<<2048, 256, 0, stream>>>(W, Wb, (unsigned)(VOCAB * DIM / 4));
        cast_bf16_kernel<<<256, 256, 0, stream>>>(hidden, Hb, (unsigned)(N_ROWS * DIM / 4));
        pcopy_kernel<<<N_ROWS, 64, 0, stream>>>(hidden, Wc, bc, pc);

        dim3 ggrid(VOCAB / TBN, N_ROWS / TBM);     // 250 x 16
        gemm_mfma_kernel<<<ggrid, 256, 0, stream>>>(Hb, Wb, bias, out, partials);

        merge_kernel<<<N_ROWS, 256, 0, stream>>>(partials, rowmax, rowsum);
        fixup_kernel<<<N_ROWS, 256, 0, stream>>>(out, attn, src, pc, rowmax, rowsum, sidx, sval);
        scalelog_kernel<<<4096, 256, 0, stream>>>(out, pc, rowmax, rowsum);
        apply_kernel<<<(N_ROWS * S_LEN + 255) / 256, 256, 0, stream>>>(sidx, sval, out);
    } else {
        float* pc     = (float*)d_ws;
        float* rowmax = pc + N_ROWS;
        float* rowsum = rowmax + N_ROWS;

        pcopy_kernel<<<N_ROWS, 64, 0, stream>>>(hidden, Wc, bc, pc);
        dim3 ggrid(VOCAB / BN, N_ROWS / BM);
        gemm_kernel<<<ggrid, 256, 0, stream>>>(hidden, W, bias, out);
        rowstat_kernel<<<N_ROWS, 256, 0, stream>>>(out, rowmax, rowsum);
        scale_kernel<<<4096, 256, 0, stream>>>(out, pc, rowmax, rowsum);
        scatter_kernel<<<(N_ROWS * S_LEN + 255) / 256, 256, 0, stream>>>(out, attn, src, pc);
        log_kernel<<<4096, 256, 0, stream>>>(out);
    }
}

// Round 5
// 404.156 us; speedup vs baseline: 2.9843x; 1.1390x over previous
//
#include <hip/hip_runtime.h>
#include <math.h>
#include <stdint.h>

#define N_ROWS 2048
#define DIM    512
#define VOCAB  32000
#define S_LEN  400
#define BATCH  32
#define NT     (VOCAB / 128)      // 250 N-tiles
#define LOG_CLIP -46.0517018598809136f   // log(1e-20)
#define HSZ    1024               // fixup LDS hash slots (>= 2*S_LEN, pow2)

typedef __attribute__((ext_vector_type(8))) short short8;
typedef __attribute__((ext_vector_type(8))) unsigned short ushort8v;
typedef __attribute__((ext_vector_type(4))) float floatx4;

__device__ inline unsigned short f32_to_bf16(float f) {
    union { float f; unsigned u; } v; v.f = f;
    unsigned u = v.u;
    return (unsigned short)((u + 0x7FFFu + ((u >> 16) & 1u)) >> 16);   // RNE
}
__device__ inline float bf16_to_f32(unsigned short h) {
    union { unsigned u; float f; } v; v.u = ((unsigned)h) << 16;
    return v.f;
}

// ---------------- kernel 0: f32 -> bf16 cast (vectorized) ----------------
__global__ void cast_bf16_kernel(const float* __restrict__ src,
                                 unsigned short* __restrict__ dst, unsigned n4) {
    for (unsigned i = blockIdx.x * blockDim.x + threadIdx.x; i < n4;
         i += gridDim.x * blockDim.x) {
        float4 v = reinterpret_cast<const float4*>(src)[i];
        ushort4 o;
        o.x = f32_to_bf16(v.x); o.y = f32_to_bf16(v.y);
        o.z = f32_to_bf16(v.z); o.w = f32_to_bf16(v.w);
        reinterpret_cast<ushort4*>(dst)[i] = o;
    }
}

// ---------------- kernel 1: p_copy = sigmoid(hidden @ Wc^T + bc) ----------------
__global__ void pcopy_kernel(const float* __restrict__ hidden,
                             const float* __restrict__ Wc,
                             const float* __restrict__ bc,
                             float* __restrict__ pc) {
    int n = blockIdx.x;
    int lane = threadIdx.x;                     // 64 threads = 1 wave
    const float4* h4 = reinterpret_cast<const float4*>(hidden + (size_t)n * DIM);
    const float4* w4 = reinterpret_cast<const float4*>(Wc);
    float acc = 0.f;
    #pragma unroll
    for (int i = lane; i < DIM / 4; i += 64) {
        float4 a = h4[i], b = w4[i];
        acc += a.x * b.x + a.y * b.y + a.z * b.z + a.w * b.w;
    }
    for (int off = 32; off > 0; off >>= 1)
        acc += __shfl_down(acc, off);
    if (lane == 0) {
        float z = acc + bc[0];
        pc[n] = 1.f / (1.f + expf(-z));
    }
}

// ---------------- kernel 2: bf16 MFMA GEMM, 2-phase dbuf, bf16 C, fused partials --
// A: [2048][512] bf16, B: [32000][512] bf16 (both K-major), C[m,v] = sum A*B (bf16 out)
#define TBM 128
#define TBN 128
#define TBK 32
#define KTILES (DIM / TBK)        // 16

__global__ __launch_bounds__(256) void gemm_mfma_kernel(
        const unsigned short* __restrict__ A,
        const unsigned short* __restrict__ B,
        const float* __restrict__ bias,
        unsigned short* __restrict__ C,          // bf16 logits
        float2* __restrict__ partials) {
    __shared__ unsigned short As[2][TBM * TBK];   // 2 x 8 KB
    __shared__ unsigned short Bs[2][TBN * TBK];   // 2 x 8 KB
    __shared__ float pmax[TBM];
    __shared__ float psum[TBM];

    const int tid  = threadIdx.x;
    const int lane = tid & 63;
    const int w    = tid >> 6;          // wave 0..3
    const int wr   = w >> 1, wc = w & 1;

    const int bm = blockIdx.y * TBM;
    const int bn = blockIdx.x * TBN;

    const int l15 = lane & 15;
    const int kg  = lane >> 4;          // 0..3

    floatx4 acc[4][4] = {};

    // staging: 8 KB tile = 512 x 16B chunks; chunk = r*256 + w*64 + lane
    // LDS dest = wave-uniform base + lane*16 (HW); global src per-lane.
    auto stage = [&](int buf, int k0) {
        #pragma unroll
        for (int r = 0; r < 2; ++r) {
            const int chunk = r * 256 + w * 64 + lane;
            const int row = chunk >> 2, cg = chunk & 3;      // 4 chunks (64B) per row
            __builtin_amdgcn_global_load_lds(
                (const __attribute__((address_space(1))) void*)(A + (size_t)(bm + row) * DIM + k0 + cg * 8),
                (__attribute__((address_space(3))) void*)(&As[buf][(size_t)(r * 256 + w * 64) * 8]),
                16, 0, 0);
        }
        #pragma unroll
        for (int r = 0; r < 2; ++r) {
            const int chunk = r * 256 + w * 64 + lane;
            const int row = chunk >> 2, cg = chunk & 3;
            __builtin_amdgcn_global_load_lds(
                (const __attribute__((address_space(1))) void*)(B + (size_t)(bn + row) * DIM + k0 + cg * 8),
                (__attribute__((address_space(3))) void*)(&Bs[buf][(size_t)(r * 256 + w * 64) * 8]),
                16, 0, 0);
        }
    };

    stage(0, 0);
    __syncthreads();                    // vmcnt(0) + barrier: tile 0 ready

    int cur = 0;
    for (int t = 0; t < KTILES; ++t) {
        if (t + 1 < KTILES) stage(cur ^ 1, (t + 1) * TBK);   // prefetch next tile

        short8 af[4], bf[4];
        #pragma unroll
        for (int m = 0; m < 4; ++m) {
            const int row = wr * 64 + m * 16 + l15;
            af[m] = *(const short8*)(&As[cur][row * TBK + kg * 8]);
        }
        #pragma unroll
        for (int n = 0; n < 4; ++n) {
            const int row = wc * 64 + n * 16 + l15;
            bf[n] = *(const short8*)(&Bs[cur][row * TBK + kg * 8]);
        }
        #pragma unroll
        for (int m = 0; m < 4; ++m)
            #pragma unroll
            for (int n = 0; n < 4; ++n)
                acc[m][n] = __builtin_amdgcn_mfma_f32_16x16x32_bf16(af[m], bf[n], acc[m][n], 0, 0, 0);

        if (t + 1 < KTILES) __syncthreads();   // drain: prefetch landed, reads done
        cur ^= 1;
    }

    // bias add + bf16 C write. C/D layout: col = lane&15, row = (lane>>4)*4 + reg [m89]
    #pragma unroll
    for (int m = 0; m < 4; ++m) {
        const int gm = bm + wr * 64 + m * 16 + kg * 4;
        #pragma unroll
        for (int n = 0; n < 4; ++n) {
            const int gn = bn + wc * 64 + n * 16 + l15;
            const float bv = bias[gn];
            #pragma unroll
            for (int r = 0; r < 4; ++r) {
                acc[m][n][r] += bv;
                C[(size_t)(gm + r) * VOCAB + gn] = f32_to_bf16(acc[m][n][r]);
            }
        }
    }

    // ---- fused per-tile softmax partials over this block's 128 columns ----
    float vmax[4][4];
    #pragma unroll
    for (int m = 0; m < 4; ++m)
        #pragma unroll
        for (int r = 0; r < 4; ++r) {
            float v = fmaxf(fmaxf(acc[m][0][r], acc[m][1][r]),
                            fmaxf(acc[m][2][r], acc[m][3][r]));
            #pragma unroll
            for (int off = 1; off < 16; off <<= 1)
                v = fmaxf(v, __shfl_xor(v, off));
            vmax[m][r] = v;
        }
    if (wc == 0 && l15 == 0)
        #pragma unroll
        for (int m = 0; m < 4; ++m)
            #pragma unroll
            for (int r = 0; r < 4; ++r)
                pmax[wr * 64 + m * 16 + kg * 4 + r] = vmax[m][r];
    __syncthreads();
    if (wc == 1 && l15 == 0)
        #pragma unroll
        for (int m = 0; m < 4; ++m)
            #pragma unroll
            for (int r = 0; r < 4; ++r) {
                const int rl = wr * 64 + m * 16 + kg * 4 + r;
                pmax[rl] = fmaxf(pmax[rl], vmax[m][r]);
            }
    __syncthreads();

    float vsum[4][4];
    #pragma unroll
    for (int m = 0; m < 4; ++m)
        #pragma unroll
        for (int r = 0; r < 4; ++r) {
            const float M = pmax[wr * 64 + m * 16 + kg * 4 + r];
            float s = expf(acc[m][0][r] - M) + expf(acc[m][1][r] - M)
                    + expf(acc[m][2][r] - M) + expf(acc[m][3][r] - M);
            #pragma unroll
            for (int off = 1; off < 16; off <<= 1)
                s += __shfl_xor(s, off);
            vsum[m][r] = s;
        }
    if (wc == 0 && l15 == 0)
        #pragma unroll
        for (int m = 0; m < 4; ++m)
            #pragma unroll
            for (int r = 0; r < 4; ++r)
                psum[wr * 64 + m * 16 + kg * 4 + r] = vsum[m][r];
    __syncthreads();
    if (wc == 1 && l15 == 0)
        #pragma unroll
        for (int m = 0; m < 4; ++m)
            #pragma unroll
            for (int r = 0; r < 4; ++r)
                psum[wr * 64 + m * 16 + kg * 4 + r] += vsum[m][r];
    __syncthreads();

    if (tid < TBM) {
        float2 p; p.x = pmax[tid]; p.y = psum[tid];
        partials[(size_t)(bm + tid) * NT + blockIdx.x] = p;
    }
}

// ---------------- kernel 3: merge per-tile partials -> rowmax / rowsum ----------------
__global__ __launch_bounds__(256) void merge_kernel(const float2* __restrict__ partials,
                                                    float* __restrict__ rowmax,
                                                    float* __restrict__ rowsum) {
    const int n = blockIdx.x;
    const int tid = threadIdx.x;
    __shared__ float red[256];

    float2 p = {0.f, 0.f};
    float m = -INFINITY;
    if (tid < NT) { p = partials[(size_t)n * NT + tid]; m = p.x; }
    red[tid] = m; __syncthreads();
    for (int s = 128; s > 0; s >>= 1) {
        if (tid < s) red[tid] = fmaxf(red[tid], red[tid + s]);
        __syncthreads();
    }
    const float M = red[0];
    __syncthreads();

    float s = (tid < NT) ? p.y * expf(p.x - M) : 0.f;
    red[tid] = s; __syncthreads();
    for (int st = 128; st > 0; st >>= 1) {
        if (tid < st) red[tid] += red[tid + st];
        __syncthreads();
    }
    if (tid == 0) { rowmax[n] = M; rowsum[n] = red[0]; }
}

// ---------------- kernel 4: fixup via LDS hash (O(S) per row) ----------------
// Dedup ids + sum attn mass in a shared hash; every s emits the identical final
// (index,value) pair for its id -> apply's duplicate writes are bit-identical.
__global__ __launch_bounds__(256) void fixup_kernel(const unsigned short* __restrict__ C,
                                                    const float* __restrict__ attn,
                                                    const int* __restrict__ src,
                                                    const float* __restrict__ pc,
                                                    const float* __restrict__ rowmax,
                                                    const float* __restrict__ rowsum,
                                                    int* __restrict__ sidx,
                                                    float* __restrict__ sval) {
    const int n = blockIdx.x;
    const int tid = threadIdx.x;
    const int b = n & (BATCH - 1);
    __shared__ int   hid[HSZ];
    __shared__ float hacc[HSZ];
    __shared__ short hslot[S_LEN];

    for (int i = tid; i < HSZ; i += 256) { hid[i] = -1; hacc[i] = 0.f; }
    __syncthreads();

    for (int s = tid; s < S_LEN; s += 256) {
        const int v = src[s * BATCH + b];
        const float a = attn[(size_t)n * S_LEN + s];
        unsigned h = (((unsigned)v) * 2654435761u >> 22) & (HSZ - 1);
        while (true) {
            int old = atomicCAS(&hid[h], -1, v);
            if (old == -1 || old == v) break;
            h = (h + 1) & (HSZ - 1);
        }
        atomicAdd(&hacc[h], a);
        hslot[s] = (short)h;
    }
    __syncthreads();

    const float m   = rowmax[n];
    const float pcn = pc[n];
    const float f   = (1.f - pcn) / rowsum[n];

    for (int s = tid; s < S_LEN; s += 256) {
        const int h = hslot[s];
        const int v = hid[h];
        const float c = hacc[h];
        const float l = bf16_to_f32(C[(size_t)n * VOCAB + v]);
        const float p = expf(l - m) * f + pcn * c;
        sidx[n * S_LEN + s] = n * VOCAB + v;
        sval[n * S_LEN + s] = logf(fmaxf(p, 1e-20f));
    }
}

// ---------------- kernel 5: fused scale+log: bf16 logits -> f32 log-probs --------
// log(max(exp(l-m)*f, 1e-20)) = max((l-m) + log f, log 1e-20)
__global__ void scalelog_kernel(const unsigned short* __restrict__ Cb,
                                float* __restrict__ out,
                                const float* __restrict__ pc,
                                const float* __restrict__ rowmax,
                                const float* __restrict__ rowsum) {
    const unsigned total8 = (unsigned)N_ROWS * (VOCAB / 8);
    for (unsigned idx = blockIdx.x * blockDim.x + threadIdx.x; idx < total8;
         idx += gridDim.x * blockDim.x) {
        const unsigned n = idx / (VOCAB / 8);
        const float lf = logf((1.f - pc[n]) / rowsum[n]) - rowmax[n];
        ushort8v raw = reinterpret_cast<const ushort8v*>(Cb)[idx];
        float4 o0, o1;
        o0.x = fmaxf(bf16_to_f32(raw[0]) + lf, LOG_CLIP);
        o0.y = fmaxf(bf16_to_f32(raw[1]) + lf, LOG_CLIP);
        o0.z = fmaxf(bf16_to_f32(raw[2]) + lf, LOG_CLIP);
        o0.w = fmaxf(bf16_to_f32(raw[3]) + lf, LOG_CLIP);
        o1.x = fmaxf(bf16_to_f32(raw[4]) + lf, LOG_CLIP);
        o1.y = fmaxf(bf16_to_f32(raw[5]) + lf, LOG_CLIP);
        o1.z = fmaxf(bf16_to_f32(raw[6]) + lf, LOG_CLIP);
        o1.w = fmaxf(bf16_to_f32(raw[7]) + lf, LOG_CLIP);
        reinterpret_cast<float4*>(out)[idx * 2]     = o0;
        reinterpret_cast<float4*>(out)[idx * 2 + 1] = o1;
    }
}

// ---------------- kernel 6: apply side-list (duplicates write identical bits) -----
__global__ void apply_kernel(const int* __restrict__ sidx,
                             const float* __restrict__ sval,
                             float* __restrict__ out) {
    const int i = blockIdx.x * blockDim.x + threadIdx.x;
    if (i >= N_ROWS * S_LEN) return;
    out[sidx[i]] = sval[i];
}

// ================= f32 fallback path (ws too small) =================
#define BM 64
#define BN 64
#define BK 16

__global__ __launch_bounds__(256) void gemm_kernel(const float* __restrict__ A,
                                                   const float* __restrict__ B,
                                                   const float* __restrict__ bias,
                                                   float* __restrict__ C) {
    __shared__ float As[BK][BM + 4];
    __shared__ float Bs[BK][BN + 4];

    const int bm = blockIdx.y * BM;
    const int bn = blockIdx.x * BN;
    const int tid = threadIdx.x;
    const int lr = tid >> 2;
    const int lk = (tid & 3) * 4;
    const int tm = (tid >> 4) * 4;
    const int tn = (tid & 15) * 4;

    float acc[4][4] = {};

    for (int k0 = 0; k0 < DIM; k0 += BK) {
        float4 a  = *reinterpret_cast<const float4*>(A + (size_t)(bm + lr) * DIM + k0 + lk);
        float4 bv = *reinterpret_cast<const float4*>(B + (size_t)(bn + lr) * DIM + k0 + lk);
        As[lk + 0][lr] = a.x;  As[lk + 1][lr] = a.y;  As[lk + 2][lr] = a.z;  As[lk + 3][lr] = a.w;
        Bs[lk + 0][lr] = bv.x; Bs[lk + 1][lr] = bv.y; Bs[lk + 2][lr] = bv.z; Bs[lk + 3][lr] = bv.w;
        __syncthreads();
        #pragma unroll
        for (int kk = 0; kk < BK; ++kk) {
            float4 av = *reinterpret_cast<const float4*>(&As[kk][tm]);
            float4 bw = *reinterpret_cast<const float4*>(&Bs[kk][tn]);
            float am[4] = {av.x, av.y, av.z, av.w};
            float bb[4] = {bw.x, bw.y, bw.z, bw.w};
            #pragma unroll
            for (int i = 0; i < 4; ++i)
                #pragma unroll
                for (int j = 0; j < 4; ++j)
                    acc[i][j] = fmaf(am[i], bb[j], acc[i][j]);
        }
        __syncthreads();
    }

    #pragma unroll
    for (int i = 0; i < 4; ++i) {
        float4 v;
        v.x = acc[i][0] + bias[bn + tn + 0];
        v.y = acc[i][1] + bias[bn + tn + 1];
        v.z = acc[i][2] + bias[bn + tn + 2];
        v.w = acc[i][3] + bias[bn + tn + 3];
        *reinterpret_cast<float4*>(C + (size_t)(bm + tm + i) * VOCAB + bn + tn) = v;
    }
}

__global__ __launch_bounds__(256) void rowstat_kernel(const float* __restrict__ logits,
                                                      float* __restrict__ rowmax,
                                                      float* __restrict__ rowsum) {
    const int n = blockIdx.x;
    const int tid = threadIdx.x;
    const float* row = logits + (size_t)n * VOCAB;
    __shared__ float red[256];

    float m = -INFINITY;
    for (int i = tid; i < VOCAB; i += 256) m = fmaxf(m, row[i]);
    red[tid] = m; __syncthreads();
    for (int s = 128; s > 0; s >>= 1) {
        if (tid < s) red[tid] = fmaxf(red[tid], red[tid + s]);
        __syncthreads();
    }
    m = red[0];
    __syncthreads();

    float sum = 0.f;
    for (int i = tid; i < VOCAB; i += 256) sum += expf(row[i] - m);
    red[tid] = sum; __syncthreads();
    for (int s = 128; s > 0; s >>= 1) {
        if (tid < s) red[tid] += red[tid + s];
        __syncthreads();
    }
    if (tid == 0) { rowmax[n] = m; rowsum[n] = red[0]; }
}

__global__ void scale_kernel(float* __restrict__ out,
                             const float* __restrict__ pc,
                             const float* __restrict__ rowmax,
                             const float* __restrict__ rowsum) {
    const unsigned total4 = (unsigned)N_ROWS * (VOCAB / 4);
    for (unsigned idx = blockIdx.x * blockDim.x + threadIdx.x; idx < total4;
         idx += gridDim.x * blockDim.x) {
        const unsigned n = idx / (VOCAB / 4);
        const float m = rowmax[n];
        const float f = (1.f - pc[n]) / rowsum[n];
        float4 v = reinterpret_cast<float4*>(out)[idx];
        v.x = expf(v.x - m) * f;
        v.y = expf(v.y - m) * f;
        v.z = expf(v.z - m) * f;
        v.w = expf(v.w - m) * f;
        reinterpret_cast<float4*>(out)[idx] = v;
    }
}

__global__ void scatter_kernel(float* __restrict__ out,
                               const float* __restrict__ attn,
                               const int* __restrict__ src,
                               const float* __restrict__ pc) {
    const int tid = blockIdx.x * blockDim.x + threadIdx.x;
    if (tid >= N_ROWS * S_LEN) return;
    const int n = tid / S_LEN;
    const int s = tid % S_LEN;
    const int b = n % BATCH;
    const int v = src[s * BATCH + b];
    atomicAdd(out + (size_t)n * VOCAB + v, attn[(size_t)n * S_LEN + s] * pc[n]);
}

__global__ void log_kernel(float* __restrict__ out) {
    const unsigned total4 = (unsigned)N_ROWS * (VOCAB / 4);
    for (unsigned idx = blockIdx.x * blockDim.x + threadIdx.x; idx < total4;
         idx += gridDim.x * blockDim.x) {
        float4 v = reinterpret_cast<float4*>(out)[idx];
        v.x = logf(fmaxf(v.x, 1e-20f));
        v.y = logf(fmaxf(v.y, 1e-20f));
        v.z = logf(fmaxf(v.z, 1e-20f));
        v.w = logf(fmaxf(v.w, 1e-20f));
        reinterpret_cast<float4*>(out)[idx] = v;
    }
}

extern "C" void kernel_launch(void* const* d_in, const int* in_sizes, int n_in,
                              void* d_out, int out_size, void* d_ws, size_t ws_size,
                              hipStream_t stream) {
    const float* hidden = (const float*)d_in[0];   // [N, D]
    const float* attn   = (const float*)d_in[1];   // [N, S]
    const int*   src    = (const int*)d_in[2];     // [S, B, 1] (int32 on device)
    const float* W      = (const float*)d_in[3];   // [V, D]
    const float* bias   = (const float*)d_in[4];   // [V]
    const float* Wc     = (const float*)d_in[5];   // [1, D]
    const float* bc     = (const float*)d_in[6];   // [1]
    float* out = (float*)d_out;                    // [N, V]

    // workspace layout (256B-aligned slots)
    const size_t wb_bytes   = (size_t)VOCAB * DIM * 2;          //  32.8 MB
    const size_t hb_bytes   = (size_t)N_ROWS * DIM * 2;         //   2.1 MB
    const size_t cb_bytes   = (size_t)N_ROWS * VOCAB * 2;       // 131.1 MB (bf16 logits)
    const size_t vec_bytes  = (size_t)N_ROWS * 4;               //   8 KB each
    const size_t part_bytes = (size_t)N_ROWS * NT * 8;          //   4.1 MB
    const size_t side_bytes = (size_t)N_ROWS * S_LEN * 4;       //   3.3 MB each

    size_t off = 0;
    auto alloc = [&](size_t bytes) { size_t o = off; off = (off + bytes + 255) & ~(size_t)255; return o; };
    char* ws = (char*)d_ws;
    const size_t o_wb   = alloc(wb_bytes);
    const size_t o_hb   = alloc(hb_bytes);
    const size_t o_cb   = alloc(cb_bytes);
    const size_t o_pc   = alloc(vec_bytes);
    const size_t o_max  = alloc(vec_bytes);
    const size_t o_sum  = alloc(vec_bytes);
    const size_t o_part = alloc(part_bytes);
    const size_t o_sidx = alloc(side_bytes);
    const size_t o_sval = alloc(side_bytes);
    const size_t need = off;

    if (ws_size >= need) {
        unsigned short* Wb = (unsigned short*)(ws + o_wb);
        unsigned short* Hb = (unsigned short*)(ws + o_hb);
        unsigned short* Cb = (unsigned short*)(ws + o_cb);
        float*  pc       = (float*)(ws + o_pc);
        float*  rowmax   = (float*)(ws + o_max);
        float*  rowsum   = (float*)(ws + o_sum);
        float2* partials = (float2*)(ws + o_part);
        int*    sidx     = (int*)(ws + o_sidx);
        float*  sval     = (float*)(ws + o_sval);

        cast_bf16_kernel<<<2048, 256, 0, stream>>>(W, Wb, (unsigned)(VOCAB * DIM / 4));
        cast_bf16_kernel<<<256, 256, 0, stream>>>(hidden, Hb, (unsigned)(N_ROWS * DIM / 4));
        pcopy_kernel<<<N_ROWS, 64, 0, stream>>>(hidden, Wc, bc, pc);

        dim3 ggrid(VOCAB / TBN, N_ROWS / TBM);     // 250 x 16
        gemm_mfma_kernel<<<ggrid, 256, 0, stream>>>(Hb, Wb, bias, Cb, partials);

        merge_kernel<<<N_ROWS, 256, 0, stream>>>(partials, rowmax, rowsum);
        fixup_kernel<<<N_ROWS, 256, 0, stream>>>(Cb, attn, src, pc, rowmax, rowsum, sidx, sval);
        scalelog_kernel<<<4096, 256, 0, stream>>>(Cb, out, pc, rowmax, rowsum);
        apply_kernel<<<(N_ROWS * S_LEN + 255) / 256, 256, 0, stream>>>(sidx, sval, out);
    } else {
        float* pc     = (float*)d_ws;
        float* rowmax = pc + N_ROWS;
        float* rowsum = rowmax + N_ROWS;

        pcopy_kernel<<<N_ROWS, 64, 0, stream>>>(hidden, Wc, bc, pc);
        dim3 ggrid(VOCAB / BN, N_ROWS / BM);
        gemm_kernel<<<ggrid, 256, 0, stream>>>(hidden, W, bias, out);
        rowstat_kernel<<<N_ROWS, 256, 0, stream>>>(out, rowmax, rowsum);
        scale_kernel<<<4096, 256, 0, stream>>>(out, pc, rowmax, rowsum);
        scatter_kernel<<<(N_ROWS * S_LEN + 255) / 256, 256, 0, stream>>>(out, attn, src, pc);
        log_kernel<<<4096, 256, 0, stream>>>(out);
    }
}